// Round 1
// baseline (46.627 us; speedup 1.0000x reference)
//
#include <hip/hip_runtime.h>

// Problem constants (match reference)
#define Bn 16
#define Kn 17
#define Hn 256
#define Wn 256
#define Mn 30
#define NFLAT (Kn * Hn * Wn)            // 1,114,112 tags per image
#define TOTAL ((long long)Bn * Kn * Hn * Wn)  // 17,825,792
#define NVEC  (TOTAL / 4)               // float4 count = 4,456,448

#define HEAT_BLOCKS 2048
#define HEAT_THREADS 256

// ---------------------------------------------------------------------------
// Kernel 1: partial sums of (pred - gt)^2 * mask, float4-vectorized grid-stride
// ---------------------------------------------------------------------------
__global__ __launch_bounds__(HEAT_THREADS) void heat_partial_kernel(
    const float4* __restrict__ pred,
    const float4* __restrict__ gt,
    const float4* __restrict__ mask,
    float* __restrict__ partial, int nvec) {
    float acc = 0.f;
    int stride = gridDim.x * blockDim.x;
    for (int i = blockIdx.x * blockDim.x + threadIdx.x; i < nvec; i += stride) {
        float4 p = pred[i];
        float4 g = gt[i];
        float4 m = mask[i];
        float dx = p.x - g.x, dy = p.y - g.y, dz = p.z - g.z, dw = p.w - g.w;
        acc += dx * dx * m.x + dy * dy * m.y + dz * dz * m.z + dw * dw * m.w;
    }
    __shared__ float s[HEAT_THREADS];
    s[threadIdx.x] = acc;
    __syncthreads();
    for (int off = HEAT_THREADS / 2; off > 0; off >>= 1) {
        if (threadIdx.x < off) s[threadIdx.x] += s[threadIdx.x + off];
        __syncthreads();
    }
    if (threadIdx.x == 0) partial[blockIdx.x] = s[0];
}

// ---------------------------------------------------------------------------
// Kernel 2: AE loss per image. 1 block (1 wave of 64) per image; lane = person.
// ---------------------------------------------------------------------------
__global__ __launch_bounds__(64) void ae_kernel(
    const float* __restrict__ tags,      // [B, NFLAT]
    const int* __restrict__ joints,      // [B, M, K, 2]
    float* __restrict__ out_push,        // [B]
    float* __restrict__ out_pull) {      // [B]
    int b = blockIdx.x;
    int lane = threadIdx.x;  // 0..63

    __shared__ float s_mu[Mn];
    __shared__ float s_valid[Mn];

    float mu = 0.f, pullpp = 0.f, validf = 0.f;
    if (lane < Mn) {
        const int* jb = joints + ((long long)(b * Mn + lane) * Kn) * 2;
        const float* tb = tags + (long long)b * NFLAT;
        float t[Kn];
        float v[Kn];
        float cnt = 0.f, st = 0.f;
#pragma unroll
        for (int k = 0; k < Kn; k++) {
            int id = jb[2 * k];
            int vi = jb[2 * k + 1];
            float tv = tb[id];
            t[k] = tv;
            v[k] = (vi > 0) ? 1.f : 0.f;
            cnt += v[k];
            st += v[k] * tv;
        }
        float sc = fmaxf(cnt, 1.f);
        mu = st / sc;
        float pp = 0.f;
#pragma unroll
        for (int k = 0; k < Kn; k++) {
            float d = t[k] - mu;
            pp += v[k] * d * d;
        }
        pullpp = pp / sc;
        validf = (cnt > 0.f) ? 1.f : 0.f;
        s_mu[lane] = mu;
        s_valid[lane] = validf;
    }
    __syncthreads();

    float nv = validf;                          // contributes to n
    float pv = (validf > 0.f) ? pullpp : 0.f;   // contributes to pull numerator
    float sm = 0.f;                             // push pairwise row sum
    if (lane < Mn && validf > 0.f) {
        for (int j = 0; j < Mn; j++) {
            if (s_valid[j] > 0.f) {
                float d = mu - s_mu[j];
                sm += expf(-(d * d));
            }
        }
    }
    // full-wave (64-lane) shuffle reduction
    for (int off = 32; off > 0; off >>= 1) {
        nv += __shfl_down(nv, off, 64);
        pv += __shfl_down(pv, off, 64);
        sm += __shfl_down(sm, off, 64);
    }
    if (lane == 0) {
        float n = nv;
        float pull = pv / fmaxf(n, 1.f);
        float denom = fmaxf((n - 1.f) * n, 1.f);
        float push = (n >= 2.f) ? (sm - n) / denom * 0.5f : 0.f;
        out_push[b] = push;
        out_pull[b] = pull;
    }
}

// ---------------------------------------------------------------------------
// Kernel 3: finalize — reduce partials (double) + average push/pull, write out
// ---------------------------------------------------------------------------
__global__ __launch_bounds__(256) void finalize_kernel(
    const float* __restrict__ partial, int nblocks,
    const float* __restrict__ push_arr,
    const float* __restrict__ pull_arr,
    float* __restrict__ out) {
    __shared__ double sd[256];
    double acc = 0.0;
    for (int i = threadIdx.x; i < nblocks; i += 256) acc += (double)partial[i];
    sd[threadIdx.x] = acc;
    __syncthreads();
    for (int off = 128; off > 0; off >>= 1) {
        if (threadIdx.x < off) sd[threadIdx.x] += sd[threadIdx.x + off];
        __syncthreads();
    }
    if (threadIdx.x == 0) {
        double heat = sd[0] / (double)TOTAL;       // HEATMAPS_LOSS_FACTOR = 1.0
        float psum = 0.f, lsum = 0.f;
        for (int b = 0; b < Bn; b++) {
            psum += push_arr[b];
            lsum += pull_arr[b];
        }
        out[0] = (float)heat;
        out[1] = (psum / (float)Bn) * 0.001f;      // PUSH_LOSS_FACTOR
        out[2] = (lsum / (float)Bn) * 0.001f;      // PULL_LOSS_FACTOR
    }
}

// ---------------------------------------------------------------------------
extern "C" void kernel_launch(void* const* d_in, const int* in_sizes, int n_in,
                              void* d_out, int out_size, void* d_ws, size_t ws_size,
                              hipStream_t stream) {
    const float* heatmaps_pred = (const float*)d_in[0];
    const float* heatmaps      = (const float*)d_in[1];
    const float* masks         = (const float*)d_in[2];
    const float* tags_pred     = (const float*)d_in[3];
    const int*   joints        = (const int*)d_in[4];
    float* out = (float*)d_out;

    float* ws = (float*)d_ws;
    float* partial  = ws;                 // [HEAT_BLOCKS]
    float* push_arr = ws + HEAT_BLOCKS;   // [Bn]
    float* pull_arr = push_arr + Bn;      // [Bn]

    heat_partial_kernel<<<HEAT_BLOCKS, HEAT_THREADS, 0, stream>>>(
        (const float4*)heatmaps_pred, (const float4*)heatmaps,
        (const float4*)masks, partial, (int)NVEC);

    ae_kernel<<<Bn, 64, 0, stream>>>(tags_pred, joints, push_arr, pull_arr);

    finalize_kernel<<<1, 256, 0, stream>>>(partial, HEAT_BLOCKS,
                                           push_arr, pull_arr, out);
}

// Round 2
// 40.839 us; speedup vs baseline: 1.1417x; 1.1417x over previous
//
#include <hip/hip_runtime.h>

// Problem constants (match reference)
#define Bn 16
#define Kn 17
#define Hn 256
#define Wn 256
#define Mn 30
#define NFLAT (Kn * Hn * Wn)                   // 1,114,112 tags per image
#define TOTAL ((long long)Bn * Kn * Hn * Wn)   // 17,825,792 elements
#define NVEC  ((int)(TOTAL / 4))               // float4 count = 4,456,448
#define NPAIR (NVEC / 2)                       // float4-pair count = 2,228,224

#define HEAT_BLOCKS 2048
#define THREADS 256
#define AE_BLOCKS Bn                           // 16 extra blocks for AE loss

// ---------------------------------------------------------------------------
// Fused kernel:
//   blocks [0, HEAT_BLOCKS)            : partial sums of (pred-gt)^2 * mask
//   blocks [HEAT_BLOCKS, +Bn)          : per-image AE (push/pull) loss
// ---------------------------------------------------------------------------
__global__ __launch_bounds__(THREADS) void fused_kernel(
    const float4* __restrict__ pred,
    const float4* __restrict__ gt,
    const float4* __restrict__ mask,
    const float* __restrict__ tags,      // [B, NFLAT]
    const int* __restrict__ joints,      // [B, M, K, 2]
    float* __restrict__ partial,         // [HEAT_BLOCKS]
    float* __restrict__ push_arr,        // [Bn]
    float* __restrict__ pull_arr) {      // [Bn]
    __shared__ float smem[64];

    if (blockIdx.x < HEAT_BLOCKS) {
        // ---------------- heatmap MSE partial ----------------
        int tid = blockIdx.x * THREADS + threadIdx.x;
        const int stride = HEAT_BLOCKS * THREADS;
        float acc0 = 0.f, acc1 = 0.f;
        for (int i = tid; i < NPAIR; i += stride) {
            float4 p0 = pred[2 * i], p1 = pred[2 * i + 1];
            float4 g0 = gt[2 * i],   g1 = gt[2 * i + 1];
            float4 m0 = mask[2 * i], m1 = mask[2 * i + 1];
            float dx, dy, dz, dw;
            dx = p0.x - g0.x; dy = p0.y - g0.y; dz = p0.z - g0.z; dw = p0.w - g0.w;
            acc0 += dx * dx * m0.x + dy * dy * m0.y + dz * dz * m0.z + dw * dw * m0.w;
            dx = p1.x - g1.x; dy = p1.y - g1.y; dz = p1.z - g1.z; dw = p1.w - g1.w;
            acc1 += dx * dx * m1.x + dy * dy * m1.y + dz * dz * m1.z + dw * dw * m1.w;
        }
        float a = acc0 + acc1;
        // intra-wave reduce (64 lanes)
        for (int off = 32; off > 0; off >>= 1) a += __shfl_down(a, off, 64);
        int wave = threadIdx.x >> 6;
        if ((threadIdx.x & 63) == 0) smem[wave] = a;
        __syncthreads();
        if (threadIdx.x == 0)
            partial[blockIdx.x] = smem[0] + smem[1] + smem[2] + smem[3];
    } else {
        // ---------------- AE (push/pull) loss, one image per block ----------
        int b = blockIdx.x - HEAT_BLOCKS;
        int lane = threadIdx.x;  // only wave 0 (lanes 0..63) participates

        float mu = 0.f, pullpp = 0.f, validf = 0.f;
        if (lane < Mn) {
            const int* jb = joints + ((long long)(b * Mn + lane) * Kn) * 2;
            const float* tb = tags + (long long)b * NFLAT;
            float t[Kn], v[Kn];
            float cnt = 0.f, st = 0.f;
#pragma unroll
            for (int k = 0; k < Kn; k++) {
                int id = jb[2 * k];
                int vi = jb[2 * k + 1];
                float tv = tb[id];
                t[k] = tv;
                v[k] = (vi > 0) ? 1.f : 0.f;
                cnt += v[k];
                st += v[k] * tv;
            }
            float sc = fmaxf(cnt, 1.f);
            mu = st / sc;
            float pp = 0.f;
#pragma unroll
            for (int k = 0; k < Kn; k++) {
                float d = t[k] - mu;
                pp += v[k] * d * d;
            }
            pullpp = pp / sc;
            validf = (cnt > 0.f) ? 1.f : 0.f;
            smem[lane] = mu;          // mu in smem[0..29]
            smem[32 + lane] = validf; // valid in smem[32..61]
        }
        __syncthreads();

        if (lane < 64) {
            float nv = validf;
            float pv = (validf > 0.f) ? pullpp : 0.f;
            float sm = 0.f;
            if (lane < Mn && validf > 0.f) {
                for (int j = 0; j < Mn; j++) {
                    if (smem[32 + j] > 0.f) {
                        float d = mu - smem[j];
                        sm += expf(-(d * d));
                    }
                }
            }
            for (int off = 32; off > 0; off >>= 1) {
                nv += __shfl_down(nv, off, 64);
                pv += __shfl_down(pv, off, 64);
                sm += __shfl_down(sm, off, 64);
            }
            if (lane == 0) {
                float n = nv;
                float pull = pv / fmaxf(n, 1.f);
                float denom = fmaxf((n - 1.f) * n, 1.f);
                float push = (n >= 2.f) ? (sm - n) / denom * 0.5f : 0.f;
                out_push:
                push_arr[b] = push;
                pull_arr[b] = pull;
            }
        }
    }
}

// ---------------------------------------------------------------------------
// Finalize: reduce partials (double) + average push/pull, write 3 outputs
// ---------------------------------------------------------------------------
__global__ __launch_bounds__(256) void finalize_kernel(
    const float* __restrict__ partial, int nblocks,
    const float* __restrict__ push_arr,
    const float* __restrict__ pull_arr,
    float* __restrict__ out) {
    __shared__ double sd[256];
    double acc = 0.0;
    for (int i = threadIdx.x; i < nblocks; i += 256) acc += (double)partial[i];
    sd[threadIdx.x] = acc;
    __syncthreads();
    for (int off = 128; off > 0; off >>= 1) {
        if (threadIdx.x < off) sd[threadIdx.x] += sd[threadIdx.x + off];
        __syncthreads();
    }
    if (threadIdx.x == 0) {
        double heat = sd[0] / (double)TOTAL;       // HEATMAPS_LOSS_FACTOR = 1.0
        float psum = 0.f, lsum = 0.f;
        for (int b = 0; b < Bn; b++) {
            psum += push_arr[b];
            lsum += pull_arr[b];
        }
        out[0] = (float)heat;
        out[1] = (psum / (float)Bn) * 0.001f;      // PUSH_LOSS_FACTOR
        out[2] = (lsum / (float)Bn) * 0.001f;      // PULL_LOSS_FACTOR
    }
}

// ---------------------------------------------------------------------------
extern "C" void kernel_launch(void* const* d_in, const int* in_sizes, int n_in,
                              void* d_out, int out_size, void* d_ws, size_t ws_size,
                              hipStream_t stream) {
    const float* heatmaps_pred = (const float*)d_in[0];
    const float* heatmaps      = (const float*)d_in[1];
    const float* masks         = (const float*)d_in[2];
    const float* tags_pred     = (const float*)d_in[3];
    const int*   joints        = (const int*)d_in[4];
    float* out = (float*)d_out;

    float* ws = (float*)d_ws;
    float* partial  = ws;                 // [HEAT_BLOCKS]
    float* push_arr = ws + HEAT_BLOCKS;   // [Bn]
    float* pull_arr = push_arr + Bn;      // [Bn]

    fused_kernel<<<HEAT_BLOCKS + AE_BLOCKS, THREADS, 0, stream>>>(
        (const float4*)heatmaps_pred, (const float4*)heatmaps,
        (const float4*)masks, tags_pred, joints, partial, push_arr, pull_arr);

    finalize_kernel<<<1, 256, 0, stream>>>(partial, HEAT_BLOCKS,
                                           push_arr, pull_arr, out);
}